// Round 1
// baseline (283.590 us; speedup 1.0000x reference)
//
#include <hip/hip_runtime.h>
#include <hip/hip_bf16.h>
#include <stdint.h>

// Problem constants: B=4, S=2048, H=16, D=1024, DK=DV=64
typedef __attribute__((ext_vector_type(8))) short bf16x8;
typedef __attribute__((ext_vector_type(4))) float f32x4;

__device__ __forceinline__ unsigned short f2bf(float f) {
  union { float f; unsigned u; } v; v.f = f;
  unsigned r = (v.u + 0x7FFFu + ((v.u >> 16) & 1u)) >> 16;
  return (unsigned short)r;
}

__device__ __forceinline__ void gload16(const void* g, void* l) {
  __builtin_amdgcn_global_load_lds(
      (const __attribute__((address_space(1))) void*)g,
      (__attribute__((address_space(3))) void*)l, 16, 0, 0);
}

// read bf16x8 from a swizzled [rows][64]bf16 LDS tile; k0 is a multiple of 8
__device__ __forceinline__ bf16x8 lds_read8(const unsigned short* base, int row, int k0) {
  int byteoff = row * 128 + (((k0 >> 3) ^ (row & 7)) << 4);
  return *(const bf16x8*)((const char*)base + byteoff);
}

// ---------------- X -> bf16 ----------------
__global__ void cvt_x_kernel(const float* __restrict__ X, unsigned short* __restrict__ Xb) {
  int i = blockIdx.x * blockDim.x + threadIdx.x;  // 1,048,576 threads, 8 elems each
  const float4* src = (const float4*)X;
  float4 a = src[2 * i];
  float4 b = src[2 * i + 1];
  bf16x8 o;
  o[0] = (short)f2bf(a.x); o[1] = (short)f2bf(a.y);
  o[2] = (short)f2bf(a.z); o[3] = (short)f2bf(a.w);
  o[4] = (short)f2bf(b.x); o[5] = (short)f2bf(b.y);
  o[6] = (short)f2bf(b.z); o[7] = (short)f2bf(b.w);
  *(bf16x8*)(Xb + (size_t)i * 8) = o;
}

// ------- pack W[h][k][e] (f32) -> Wbt[p][n=h*64+e][k] (bf16, transposed) -------
__global__ void cvt_w_kernel(const float* __restrict__ Wq, const float* __restrict__ Wk,
                             const float* __restrict__ Wv, unsigned short* __restrict__ Wbt) {
  __shared__ float t[64][65];
  const int k0 = blockIdx.x * 64;
  const int h  = blockIdx.y;
  const int p  = blockIdx.z;
  const float* W = (p == 0 ? Wq : (p == 1 ? Wk : Wv)) + (size_t)h * 1024 * 64;
  const int tid = threadIdx.x;
  {
    int e = tid & 63, kq = tid >> 6;
#pragma unroll
    for (int i = 0; i < 16; ++i) {
      int k = i * 4 + kq;
      t[k][e] = W[(size_t)(k0 + k) * 64 + e];
    }
  }
  __syncthreads();
  {
    int k = tid & 63, eq = tid >> 6;
#pragma unroll
    for (int i = 0; i < 16; ++i) {
      int e = i * 4 + eq;
      Wbt[(size_t)((p * 1024) + h * 64 + e) * 1024 + k0 + k] = f2bf(t[k][e]);
    }
  }
}

// ---------------- projection GEMM: [8192,1024] x [1024,1024] per p ----------------
// C[m][n]: m=(b,s), n=(h,e).  p=0 -> Qb (pre-scaled 1/8), p=1 -> Kb, p=2 -> Vt (transposed)
__global__ __launch_bounds__(256, 2) void proj_gemm(
    const unsigned short* __restrict__ Xb,   // [8192][1024]
    const unsigned short* __restrict__ Wbt,  // [3][1024 n][1024 k]
    unsigned short* __restrict__ Qb,         // [64 bh][2048 s][64 e]
    unsigned short* __restrict__ Kb,         // [64 bh][2048 s][64 e]
    unsigned short* __restrict__ Vt) {       // [64 bh][64 e][2048 s]
  __shared__ unsigned short As[128 * 64];
  __shared__ unsigned short Bs[128 * 64];
  const int m0 = blockIdx.x * 128;
  const int n0 = blockIdx.y * 128;
  const int p  = blockIdx.z;
  const int tid = threadIdx.x;
  const int lane = tid & 63;
  const int wid = tid >> 6;
  const int wr = wid >> 1, wc = wid & 1;

  const unsigned short* Ag = Xb + (size_t)m0 * 1024;
  const unsigned short* Bg = Wbt + (size_t)p * 1024 * 1024 + (size_t)n0 * 1024;

  f32x4 acc[4][4];
#pragma unroll
  for (int i = 0; i < 4; ++i)
#pragma unroll
    for (int j = 0; j < 4; ++j) acc[i][j] = (f32x4){0.f, 0.f, 0.f, 0.f};

  for (int kt = 0; kt < 16; ++kt) {
#pragma unroll
    for (int i = 0; i < 4; ++i) {
      int row0 = wid * 32 + i * 8;
      int lr = row0 + (lane >> 3);
      int slot = (lane & 7) ^ (lr & 7);
      gload16(Ag + (size_t)lr * 1024 + kt * 64 + slot * 8, (char*)As + row0 * 128);
      gload16(Bg + (size_t)lr * 1024 + kt * 64 + slot * 8, (char*)Bs + row0 * 128);
    }
    __syncthreads();
#pragma unroll
    for (int ks = 0; ks < 2; ++ks) {
      int k0 = ks * 32 + (lane >> 4) * 8;
      bf16x8 a[4], b[4];
#pragma unroll
      for (int mi = 0; mi < 4; ++mi) a[mi] = lds_read8(As, wr * 64 + mi * 16 + (lane & 15), k0);
#pragma unroll
      for (int ni = 0; ni < 4; ++ni) b[ni] = lds_read8(Bs, wc * 64 + ni * 16 + (lane & 15), k0);
#pragma unroll
      for (int mi = 0; mi < 4; ++mi)
#pragma unroll
        for (int ni = 0; ni < 4; ++ni)
          acc[mi][ni] = __builtin_amdgcn_mfma_f32_16x16x32_bf16(a[mi], b[ni], acc[mi][ni], 0, 0, 0);
    }
    __syncthreads();
  }

  // epilogue: scatter to Q/K (row-major [bh][s][e]) or V transposed ([bh][e][s])
#pragma unroll
  for (int mi = 0; mi < 4; ++mi) {
    int m = m0 + wr * 64 + mi * 16 + ((lane >> 4) << 2);
    int bb = m >> 11;         // /2048
    int s  = m & 2047;
#pragma unroll
    for (int ni = 0; ni < 4; ++ni) {
      int n = n0 + wc * 64 + ni * 16 + (lane & 15);
      int h = n >> 6, e = n & 63;
#pragma unroll
      for (int r = 0; r < 4; ++r) {
        float v = acc[mi][ni][r];
        int sr = s + r;
        if (p == 0) {
          Qb[((size_t)(bb * 16 + h) * 2048 + sr) * 64 + e] = f2bf(v * 0.125f);  // fold 1/sqrt(64)
        } else if (p == 1) {
          Kb[((size_t)(bb * 16 + h) * 2048 + sr) * 64 + e] = f2bf(v);
        } else {
          Vt[((size_t)(bb * 16 + h) * 64 + e) * 2048 + sr] = f2bf(v);
        }
      }
    }
  }
}

// ---------------- flash attention: per (b,h), Q-tile 128, K-tile 64 ----------------
__global__ __launch_bounds__(256, 2) void attn_kernel(
    const unsigned short* __restrict__ Qb,  // [bh][s][64], pre-scaled
    const unsigned short* __restrict__ Kb,  // [bh][s][64]
    const unsigned short* __restrict__ Vt,  // [bh][e][s]
    float* __restrict__ out) {              // [b][s][h*64+e]
  __shared__ unsigned short Ks[64 * 64];       // [key][dim] swizzled
  __shared__ unsigned short Vs[64 * 64];       // [e][s]    swizzled
  __shared__ unsigned short Ps[4 * 32 * 64];   // per-wave [32 q][64 key] swizzled
  const int bh = blockIdx.y;
  const int q0 = blockIdx.x * 128;
  const int tid = threadIdx.x;
  const int lane = tid & 63;
  const int wid = tid >> 6;
  const unsigned short* Qp = Qb + (size_t)bh * 2048 * 64;
  const unsigned short* Kp = Kb + (size_t)bh * 2048 * 64;
  const unsigned short* Vp = Vt + (size_t)bh * 64 * 2048;
  unsigned short* Pw = Ps + wid * 32 * 64;

  // Q fragments in registers: 2 M-frags x 2 K-steps
  bf16x8 qf[2][2];
#pragma unroll
  for (int mi = 0; mi < 2; ++mi)
#pragma unroll
    for (int ks = 0; ks < 2; ++ks)
      qf[mi][ks] = *(const bf16x8*)(Qp + ((size_t)(q0 + wid * 32 + mi * 16 + (lane & 15))) * 64 +
                                    ks * 32 + (lane >> 4) * 8);

  f32x4 acc_o[2][4];
#pragma unroll
  for (int mi = 0; mi < 2; ++mi)
#pragma unroll
    for (int nv = 0; nv < 4; ++nv) acc_o[mi][nv] = (f32x4){0.f, 0.f, 0.f, 0.f};
  float mrow[2][4], lrow[2][4];
#pragma unroll
  for (int mi = 0; mi < 2; ++mi)
#pragma unroll
    for (int r = 0; r < 4; ++r) { mrow[mi][r] = -1e30f; lrow[mi][r] = 0.f; }

  for (int kt = 0; kt < 32; ++kt) {
    // stage K-tile [64 key][64 dim] and V-tile [64 e][64 s]
#pragma unroll
    for (int i = 0; i < 2; ++i) {
      int row0 = wid * 16 + i * 8;
      int lr = row0 + (lane >> 3);
      int slot = (lane & 7) ^ (lr & 7);
      gload16(Kp + (size_t)(kt * 64 + lr) * 64 + slot * 8, (char*)Ks + row0 * 128);
      gload16(Vp + (size_t)lr * 2048 + kt * 64 + slot * 8, (char*)Vs + row0 * 128);
    }
    __syncthreads();

    // S = Q K^T (Q pre-scaled by 1/8)
    f32x4 sc[2][4];
#pragma unroll
    for (int mi = 0; mi < 2; ++mi)
#pragma unroll
      for (int ni = 0; ni < 4; ++ni) sc[mi][ni] = (f32x4){0.f, 0.f, 0.f, 0.f};
#pragma unroll
    for (int ks = 0; ks < 2; ++ks) {
      int k0 = ks * 32 + (lane >> 4) * 8;
      bf16x8 kf[4];
#pragma unroll
      for (int ni = 0; ni < 4; ++ni) kf[ni] = lds_read8(Ks, ni * 16 + (lane & 15), k0);
#pragma unroll
      for (int mi = 0; mi < 2; ++mi)
#pragma unroll
        for (int ni = 0; ni < 4; ++ni)
          sc[mi][ni] = __builtin_amdgcn_mfma_f32_16x16x32_bf16(qf[mi][ks], kf[ni], sc[mi][ni], 0, 0, 0);
    }

    // online softmax (row stats per (mi, r); row-reduce over the 16-lane col groups)
#pragma unroll
    for (int mi = 0; mi < 2; ++mi) {
      float tm[4], rs[4], pv[4][4];
#pragma unroll
      for (int r = 0; r < 4; ++r)
        tm[r] = fmaxf(fmaxf(sc[mi][0][r], sc[mi][1][r]), fmaxf(sc[mi][2][r], sc[mi][3][r]));
#pragma unroll
      for (int off = 1; off < 16; off <<= 1)
#pragma unroll
        for (int r = 0; r < 4; ++r) tm[r] = fmaxf(tm[r], __shfl_xor(tm[r], off, 64));
#pragma unroll
      for (int r = 0; r < 4; ++r) {
        float mo = mrow[mi][r];
        float mn = fmaxf(mo, tm[r]);
        float corr = __expf(mo - mn);
        mrow[mi][r] = mn;
        lrow[mi][r] *= corr;
#pragma unroll
        for (int nv = 0; nv < 4; ++nv) acc_o[mi][nv][r] *= corr;
        rs[r] = 0.f;
#pragma unroll
        for (int ni = 0; ni < 4; ++ni) {
          float pe = __expf(sc[mi][ni][r] - mn);
          pv[ni][r] = pe;
          rs[r] += pe;
        }
      }
#pragma unroll
      for (int off = 1; off < 16; off <<= 1)
#pragma unroll
        for (int r = 0; r < 4; ++r) rs[r] += __shfl_xor(rs[r], off, 64);
#pragma unroll
      for (int r = 0; r < 4; ++r) lrow[mi][r] += rs[r];
      // P -> per-wave LDS (bf16, swizzled), C-layout -> row-major
#pragma unroll
      for (int ni = 0; ni < 4; ++ni)
#pragma unroll
        for (int r = 0; r < 4; ++r) {
          int row = mi * 16 + ((lane >> 4) << 2) + r;
          int col = ni * 16 + (lane & 15);
          int byteoff = row * 128 + (((col >> 3) ^ (row & 7)) << 4) + (col & 7) * 2;
          *(unsigned short*)((char*)Pw + byteoff) = f2bf(pv[ni][r]);
        }
    }

    // O += P V   (A = P[32 q][64 key] from LDS, B = V[key][e] via Vt rows)
#pragma unroll
    for (int ks = 0; ks < 2; ++ks) {
      int k0 = ks * 32 + (lane >> 4) * 8;
      bf16x8 pf[2], vf[4];
#pragma unroll
      for (int mi = 0; mi < 2; ++mi) pf[mi] = lds_read8(Pw, mi * 16 + (lane & 15), k0);
#pragma unroll
      for (int nv = 0; nv < 4; ++nv) vf[nv] = lds_read8(Vs, nv * 16 + (lane & 15), k0);
#pragma unroll
      for (int mi = 0; mi < 2; ++mi)
#pragma unroll
        for (int nv = 0; nv < 4; ++nv)
          acc_o[mi][nv] = __builtin_amdgcn_mfma_f32_16x16x32_bf16(pf[mi], vf[nv], acc_o[mi][nv], 0, 0, 0);
    }
    __syncthreads();
  }

  const int b = bh >> 4, h = bh & 15;
#pragma unroll
  for (int mi = 0; mi < 2; ++mi) {
    int srow = q0 + wid * 32 + mi * 16 + ((lane >> 4) << 2);
#pragma unroll
    for (int nv = 0; nv < 4; ++nv) {
      int col = h * 64 + nv * 16 + (lane & 15);
#pragma unroll
      for (int r = 0; r < 4; ++r)
        out[((size_t)(b * 2048 + srow + r)) * 1024 + col] = acc_o[mi][nv][r] / lrow[mi][r];
    }
  }
}

extern "C" void kernel_launch(void* const* d_in, const int* in_sizes, int n_in,
                              void* d_out, int out_size, void* d_ws, size_t ws_size,
                              hipStream_t stream) {
  (void)in_sizes; (void)n_in; (void)out_size; (void)ws_size;
  const float* X  = (const float*)d_in[0];
  const float* Wq = (const float*)d_in[1];
  const float* Wk = (const float*)d_in[2];
  const float* Wv = (const float*)d_in[3];
  float* out = (float*)d_out;

  unsigned short* Xb  = (unsigned short*)d_ws;              // 8192*1024
  unsigned short* Wbt = Xb + (size_t)8192 * 1024;           // 3*1024*1024
  unsigned short* Qb  = Wbt + (size_t)3 * 1024 * 1024;      // 64*2048*64
  unsigned short* Kb  = Qb + (size_t)64 * 2048 * 64;
  unsigned short* Vt  = Kb + (size_t)64 * 2048 * 64;        // total ~73.4 MB

  hipLaunchKernelGGL(cvt_x_kernel, dim3(4096), dim3(256), 0, stream, X, Xb);
  hipLaunchKernelGGL(cvt_w_kernel, dim3(16, 16, 3), dim3(256), 0, stream, Wq, Wk, Wv, Wbt);
  hipLaunchKernelGGL(proj_gemm, dim3(64, 8, 3), dim3(256), 0, stream, Xb, Wbt, Qb, Kb, Vt);
  hipLaunchKernelGGL(attn_kernel, dim3(16, 64), dim3(256), 0, stream, Qb, Kb, Vt, out);
}

// Round 2
// 194.881 us; speedup vs baseline: 1.4552x; 1.4552x over previous
//
#include <hip/hip_runtime.h>
#include <hip/hip_bf16.h>
#include <stdint.h>

// Problem constants: B=4, S=2048, H=16, D=1024, DK=DV=64
typedef __attribute__((ext_vector_type(8))) short bf16x8;
typedef __attribute__((ext_vector_type(4))) float f32x4;
typedef __attribute__((ext_vector_type(16))) float f32x16;

__device__ __forceinline__ unsigned short f2bf(float f) {
  union { float f; unsigned u; } v; v.f = f;
  unsigned r = (v.u + 0x7FFFu + ((v.u >> 16) & 1u)) >> 16;
  return (unsigned short)r;
}

__device__ __forceinline__ void gload16(const void* g, void* l) {
  __builtin_amdgcn_global_load_lds(
      (const __attribute__((address_space(1))) void*)g,
      (__attribute__((address_space(3))) void*)l, 16, 0, 0);
}

// read bf16x8 from a swizzled [rows][64]bf16 LDS tile; k0 is a multiple of 8
__device__ __forceinline__ bf16x8 lds_read8(const unsigned short* base, int row, int k0) {
  int byteoff = row * 128 + (((k0 >> 3) ^ (row & 7)) << 4);
  return *(const bf16x8*)((const char*)base + byteoff);
}

// read 4 bf16 (8B) at column c (multiple of 4) from the same swizzled tile
__device__ __forceinline__ unsigned long long lds_read4(const unsigned short* base, int row, int c) {
  int bir = c * 2;  // byte-in-row, 8B aligned
  int byteoff = row * 128 + (((bir >> 4) ^ (row & 7)) << 4) + (bir & 15);
  return *(const unsigned long long*)((const char*)base + byteoff);
}

__device__ __forceinline__ unsigned int cvtpk(float a, float b) {
  unsigned int r;
  asm("v_cvt_pk_bf16_f32 %0, %1, %2" : "=v"(r) : "v"(a), "v"(b));
  return r;
}

// ---------------- X -> bf16 ----------------
__global__ void cvt_x_kernel(const float* __restrict__ X, unsigned short* __restrict__ Xb) {
  int i = blockIdx.x * blockDim.x + threadIdx.x;
  const float4* src = (const float4*)X;
  float4 a = src[2 * i];
  float4 b = src[2 * i + 1];
  bf16x8 o;
  o[0] = (short)f2bf(a.x); o[1] = (short)f2bf(a.y);
  o[2] = (short)f2bf(a.z); o[3] = (short)f2bf(a.w);
  o[4] = (short)f2bf(b.x); o[5] = (short)f2bf(b.y);
  o[6] = (short)f2bf(b.z); o[7] = (short)f2bf(b.w);
  *(bf16x8*)(Xb + (size_t)i * 8) = o;
}

// ------- pack W[h][k][e] (f32) -> Wbt[p][n=h*64+e][k] (bf16, transposed) -------
__global__ void cvt_w_kernel(const float* __restrict__ Wq, const float* __restrict__ Wk,
                             const float* __restrict__ Wv, unsigned short* __restrict__ Wbt) {
  __shared__ float t[64][65];
  const int k0 = blockIdx.x * 64;
  const int h  = blockIdx.y;
  const int p  = blockIdx.z;
  const float* W = (p == 0 ? Wq : (p == 1 ? Wk : Wv)) + (size_t)h * 1024 * 64;
  const int tid = threadIdx.x;
  {
    int e = tid & 63, kq = tid >> 6;
#pragma unroll
    for (int i = 0; i < 16; ++i) {
      int k = i * 4 + kq;
      t[k][e] = W[(size_t)(k0 + k) * 64 + e];
    }
  }
  __syncthreads();
  {
    int k = tid & 63, eq = tid >> 6;
#pragma unroll
    for (int i = 0; i < 16; ++i) {
      int e = i * 4 + eq;
      Wbt[(size_t)((p * 1024) + h * 64 + e) * 1024 + k0 + k] = f2bf(t[k][e]);
    }
  }
}

// ---------------- projection GEMM: [8192,1024] x [1024,1024] per p ----------------
// p=0 -> Qb (pre-scaled by 0.125*log2(e)), p=1 -> Kb, p=2 -> Vt (transposed)
__global__ __launch_bounds__(256, 2) void proj_gemm(
    const unsigned short* __restrict__ Xb,   // [8192][1024]
    const unsigned short* __restrict__ Wbt,  // [3][1024 n][1024 k]
    unsigned short* __restrict__ Qb,         // [64 bh][2048 s][64 e]
    unsigned short* __restrict__ Kb,         // [64 bh][2048 s][64 e]
    unsigned short* __restrict__ Vt) {       // [64 bh][64 e][2048 s]
  __shared__ unsigned short As[128 * 64];
  __shared__ unsigned short Bs[128 * 64];
  const int m0 = blockIdx.x * 128;
  const int n0 = blockIdx.y * 128;
  const int p  = blockIdx.z;
  const int tid = threadIdx.x;
  const int lane = tid & 63;
  const int wid = tid >> 6;
  const int wr = wid >> 1, wc = wid & 1;

  const unsigned short* Ag = Xb + (size_t)m0 * 1024;
  const unsigned short* Bg = Wbt + (size_t)p * 1024 * 1024 + (size_t)n0 * 1024;

  f32x4 acc[4][4];
#pragma unroll
  for (int i = 0; i < 4; ++i)
#pragma unroll
    for (int j = 0; j < 4; ++j) acc[i][j] = (f32x4){0.f, 0.f, 0.f, 0.f};

  for (int kt = 0; kt < 16; ++kt) {
#pragma unroll
    for (int i = 0; i < 4; ++i) {
      int row0 = wid * 32 + i * 8;
      int lr = row0 + (lane >> 3);
      int slot = (lane & 7) ^ (lr & 7);
      gload16(Ag + (size_t)lr * 1024 + kt * 64 + slot * 8, (char*)As + row0 * 128);
      gload16(Bg + (size_t)lr * 1024 + kt * 64 + slot * 8, (char*)Bs + row0 * 128);
    }
    __syncthreads();
#pragma unroll
    for (int ks = 0; ks < 2; ++ks) {
      int k0 = ks * 32 + (lane >> 4) * 8;
      bf16x8 a[4], b[4];
#pragma unroll
      for (int mi = 0; mi < 4; ++mi) a[mi] = lds_read8(As, wr * 64 + mi * 16 + (lane & 15), k0);
#pragma unroll
      for (int ni = 0; ni < 4; ++ni) b[ni] = lds_read8(Bs, wc * 64 + ni * 16 + (lane & 15), k0);
#pragma unroll
      for (int mi = 0; mi < 4; ++mi)
#pragma unroll
        for (int ni = 0; ni < 4; ++ni)
          acc[mi][ni] = __builtin_amdgcn_mfma_f32_16x16x32_bf16(a[mi], b[ni], acc[mi][ni], 0, 0, 0);
    }
    __syncthreads();
  }

#pragma unroll
  for (int mi = 0; mi < 4; ++mi) {
    int m = m0 + wr * 64 + mi * 16 + ((lane >> 4) << 2);
    int bb = m >> 11;
    int s  = m & 2047;
#pragma unroll
    for (int ni = 0; ni < 4; ++ni) {
      int n = n0 + wc * 64 + ni * 16 + (lane & 15);
      int h = n >> 6, e = n & 63;
#pragma unroll
      for (int r = 0; r < 4; ++r) {
        float v = acc[mi][ni][r];
        int sr = s + r;
        if (p == 0) {
          // fold 1/sqrt(64) * log2(e): scores end up in log2 domain
          Qb[((size_t)(bb * 16 + h) * 2048 + sr) * 64 + e] = f2bf(v * 0.18033688f);
        } else if (p == 1) {
          Kb[((size_t)(bb * 16 + h) * 2048 + sr) * 64 + e] = f2bf(v);
        } else {
          Vt[((size_t)(bb * 16 + h) * 64 + e) * 2048 + sr] = f2bf(v);
        }
      }
    }
  }
}

// ---------------- flash attention: swapped 32x32 MFMA, per (b,h) ----------------
// Each wave: 32 q rows; block: 4 waves = 128 q. KV staged 64/iter, double-buffered.
__global__ __launch_bounds__(256, 4) void attn_kernel(
    const unsigned short* __restrict__ Qb,  // [bh][s][64], pre-scaled (log2 domain)
    const unsigned short* __restrict__ Kb,  // [bh][s][64]
    const unsigned short* __restrict__ Vt,  // [bh][e][s]
    float* __restrict__ out) {              // [b][s][h*64+e]
  __shared__ unsigned short smem[16384];    // [2 buf][ K 4096 | V 4096 ] shorts = 32KB
  const int bh = blockIdx.x;                // x = bh so XCD round-robin groups 8 heads/XCD
  const int q0 = blockIdx.y * 128;
  const int tid = threadIdx.x;
  const int lane = tid & 63;
  const int wid = tid >> 6;
  const int ql = lane & 31;   // q_local (C column)
  const int hi = lane >> 5;

  const unsigned short* Qp = Qb + (size_t)bh * 2048 * 64;
  const unsigned short* Kp = Kb + (size_t)bh * 2048 * 64;
  const unsigned short* Vp = Vt + (size_t)bh * 64 * 2048;

  // Q row-fragments (B operand): 4 k-steps of 16 over d=64
  bf16x8 qf[4];
#pragma unroll
  for (int ks = 0; ks < 4; ++ks)
    qf[ks] = *(const bf16x8*)(Qp + (size_t)(q0 + wid * 32 + ql) * 64 + ks * 16 + hi * 8);

  f32x16 acc[2];
#pragma unroll
  for (int mi = 0; mi < 2; ++mi)
#pragma unroll
    for (int i = 0; i < 16; ++i) acc[mi][i] = 0.f;
  float m = -1e30f, l = 0.f;

  auto STAGE = [&](int buf, int kt) {
    unsigned short* Ks = smem + buf * 8192;
    unsigned short* Vs = Ks + 4096;
#pragma unroll
    for (int i = 0; i < 2; ++i) {
      int row0 = wid * 16 + i * 8;      // wave-uniform LDS dest base
      int lr = row0 + (lane >> 3);
      int slot = (lane & 7) ^ (lr & 7);
      gload16(Kp + (size_t)(kt * 64 + lr) * 64 + slot * 8, (char*)Ks + row0 * 128);
      gload16(Vp + (size_t)lr * 2048 + kt * 64 + slot * 8, (char*)Vs + row0 * 128);
    }
  };

  STAGE(0, 0);
  asm volatile("s_waitcnt vmcnt(0)" ::: "memory");
  __builtin_amdgcn_s_barrier();

  int cur = 0;
  for (int kt = 0; kt < 32; ++kt) {
    if (kt < 31) STAGE(cur ^ 1, kt + 1);   // prefetch next tile under compute
    const unsigned short* Ks = smem + cur * 8192;
    const unsigned short* Vs = Ks + 4096;

#pragma unroll
    for (int t = 0; t < 2; ++t) {          // two 32-key subtiles
      // S^T = K·Q^T : C[key][q], col=lane&31=q, row=(r&3)+8*(r>>2)+4*hi=key_local
      f32x16 s;
#pragma unroll
      for (int i = 0; i < 16; ++i) s[i] = 0.f;
#pragma unroll
      for (int ks = 0; ks < 4; ++ks) {
        bf16x8 kf = lds_read8(Ks, t * 32 + ql, ks * 16 + hi * 8);
        s = __builtin_amdgcn_mfma_f32_32x32x16_bf16(kf, qf[ks], s, 0, 0, 0);
      }

      // row max over this lane's 16 keys (tree), then combine with partner half
      float tmx[8];
#pragma unroll
      for (int i = 0; i < 8; ++i) tmx[i] = fmaxf(s[i], s[i + 8]);
#pragma unroll
      for (int st = 4; st >= 1; st >>= 1)
#pragma unroll
        for (int i = 0; i < 4; ++i) if (i < st) tmx[i] = fmaxf(tmx[i], tmx[i + st]);
      float tmax = fmaxf(tmx[0], __shfl_xor(tmx[0], 32, 64));

      // defer-max (log2 units, THR=8 -> P <= 256)
      if (!__all(tmax <= m + 8.0f)) {
        float mn = fmaxf(m, tmax);
        float corr = exp2f(m - mn);
        m = mn;
        l *= corr;
#pragma unroll
        for (int mi = 0; mi < 2; ++mi)
#pragma unroll
          for (int i = 0; i < 16; ++i) acc[mi][i] *= corr;
      }

      float p[16];
#pragma unroll
      for (int i = 0; i < 16; ++i) p[i] = exp2f(s[i] - m);
      {  // tree-sum into l (avoid serial dependency chain)
        float a0 = (p[0] + p[1]) + (p[2] + p[3]);
        float a1 = (p[4] + p[5]) + (p[6] + p[7]);
        float a2 = (p[8] + p[9]) + (p[10] + p[11]);
        float a3 = (p[12] + p[13]) + (p[14] + p[15]);
        l += (a0 + a1) + (a2 + a3);
      }

      // pack P row-fragments: k-step0 = p[0..7], k-step1 = p[8..15] (lane-local!)
      union { unsigned int u[4]; bf16x8 v; } P0, P1;
#pragma unroll
      for (int j = 0; j < 4; ++j) {
        P0.u[j] = cvtpk(p[2 * j], p[2 * j + 1]);
        P1.u[j] = cvtpk(p[8 + 2 * j], p[8 + 2 * j + 1]);
      }

      // O^T += V^T · P^T  with V-side k-slots permuted to match P residency:
      // A slot (hi,j) holds V^T[e][t*32 + ks*16 + 4*hi + (j&3) + 8*(j>>2)]
#pragma unroll
      for (int mi = 0; mi < 2; ++mi) {
#pragma unroll
        for (int ks = 0; ks < 2; ++ks) {
          union { unsigned long long q[2]; bf16x8 v; } V;
          int c1 = t * 32 + ks * 16 + hi * 4;
          V.q[0] = lds_read4(Vs, mi * 32 + ql, c1);
          V.q[1] = lds_read4(Vs, mi * 32 + ql, c1 + 8);
          acc[mi] = __builtin_amdgcn_mfma_f32_32x32x16_bf16(V.v, ks ? P1.v : P0.v, acc[mi], 0, 0, 0);
        }
      }
    }
    asm volatile("s_waitcnt vmcnt(0)" ::: "memory");
    __builtin_amdgcn_s_barrier();
    cur ^= 1;
  }

  __builtin_amdgcn_s_barrier();  // all waves done reading K/V LDS before reuse

  // epilogue: O^T -> LDS (xor-swizzled) -> coalesced global rows
  float lf = l + __shfl_xor(l, 32, 64);
  float inv = 1.0f / lf;
  float* fs = (float*)smem + wid * 2048;   // 32 q x 64 e per wave
#pragma unroll
  for (int mi = 0; mi < 2; ++mi)
#pragma unroll
    for (int r = 0; r < 16; ++r) {
      int e = mi * 32 + (r & 3) + 8 * (r >> 2) + 4 * hi;
      fs[ql * 64 + (e ^ ql)] = acc[mi][r] * inv;
    }
  const int b = bh >> 4, h = bh & 15;
#pragma unroll
  for (int i = 0; i < 32; ++i) {
    float v = fs[i * 64 + (lane ^ i)];
    out[((size_t)(b * 2048 + q0 + wid * 32 + i)) * 1024 + h * 64 + lane] = v;
  }
}

extern "C" void kernel_launch(void* const* d_in, const int* in_sizes, int n_in,
                              void* d_out, int out_size, void* d_ws, size_t ws_size,
                              hipStream_t stream) {
  (void)in_sizes; (void)n_in; (void)out_size; (void)ws_size;
  const float* X  = (const float*)d_in[0];
  const float* Wq = (const float*)d_in[1];
  const float* Wk = (const float*)d_in[2];
  const float* Wv = (const float*)d_in[3];
  float* out = (float*)d_out;

  unsigned short* Xb  = (unsigned short*)d_ws;              // 8192*1024
  unsigned short* Wbt = Xb + (size_t)8192 * 1024;           // 3*1024*1024
  unsigned short* Qb  = Wbt + (size_t)3 * 1024 * 1024;      // 64*2048*64
  unsigned short* Kb  = Qb + (size_t)64 * 2048 * 64;
  unsigned short* Vt  = Kb + (size_t)64 * 2048 * 64;        // total ~73.4 MB

  hipLaunchKernelGGL(cvt_x_kernel, dim3(4096), dim3(256), 0, stream, X, Xb);
  hipLaunchKernelGGL(cvt_w_kernel, dim3(16, 16, 3), dim3(256), 0, stream, Wq, Wk, Wv, Wbt);
  hipLaunchKernelGGL(proj_gemm, dim3(64, 8, 3), dim3(256), 0, stream, Xb, Wbt, Qb, Kb, Vt);
  hipLaunchKernelGGL(attn_kernel, dim3(64, 16), dim3(256), 0, stream, Qb, Kb, Vt, out);
}